// Round 3
// baseline (679.560 us; speedup 1.0000x reference)
//
#include <hip/hip_runtime.h>
#include <hip/hip_bf16.h>

// GCN 2-layer + classifier, fp32.
// x:[n,64] edge_index:[2,E] int32, W1:[64,64] b1:[64] W2:[64,64] b2:[64] Wc:[64,16] bc:[16]
// out:[n,16] fp32.
// CSR-by-dst built per launch via 2-level counting sort:
//   pass1: scatter {src,dst} into 196 bucket regions (bucket = dst>>8) with per-bucket
//          atomic cursors -> sequential writes, write-amp ~1 (vs 8x for full random scatter)
//   pass2: one WG per bucket, per-node cursors in LDS, writes {src, inv[src]} into the
//          bucket's contiguous window of cw -> L2-coalesced. No global cnt array.
// k_agg: wave per node, lane per feature, masked unroll x8 (8 gathers in flight).

#define FDIM 64
#define NCLS 16

__global__ __launch_bounds__(256) void k_deg(const int* __restrict__ dst, int E, int* __restrict__ deg) {
    int e = blockIdx.x * 256 + threadIdx.x;
    if (e < E) atomicAdd(&deg[dst[e]], 1);
}

// inv = rsqrt(deg+1) fused with per-block (=per-bucket, 256 nodes) degree sums
__global__ __launch_bounds__(256) void k_prep(const int* __restrict__ deg, int n,
                                              float* __restrict__ inv, int* __restrict__ bsum) {
    __shared__ int s[256];
    int t = threadIdx.x;
    int i = blockIdx.x * 256 + t;
    int d = (i < n) ? deg[i] : 0;
    if (i < n) inv[i] = rsqrtf((float)(d + 1));
    s[t] = d;
    __syncthreads();
    for (int off = 128; off > 0; off >>= 1) {
        if (t < off) s[t] += s[t + off];
        __syncthreads();
    }
    if (t == 0) bsum[blockIdx.x] = s[0];
}

// single block, nb <= 256: exclusive scan of bsum; also copy to bcur (mutable cursors)
__global__ __launch_bounds__(256) void k_scan_bsums(int* __restrict__ bsum, int nb,
                                                    int* __restrict__ bcur) {
    __shared__ int s[256];
    int t = threadIdx.x;
    int v = (t < nb) ? bsum[t] : 0;
    s[t] = v;
    __syncthreads();
    for (int off = 1; off < 256; off <<= 1) {
        int add = (t >= off) ? s[t - off] : 0;
        __syncthreads();
        s[t] += add;
        __syncthreads();
    }
    if (t < nb) {
        int ex = s[t] - v;   // exclusive
        bsum[t] = ex;
        bcur[t] = ex;
    }
}

__global__ __launch_bounds__(256) void k_scan_chunks(const int* __restrict__ deg, int n,
                                                     const int* __restrict__ bsum, int* __restrict__ row_ptr) {
    __shared__ int s[256];
    int t = threadIdx.x;
    int i = blockIdx.x * 256 + t;
    int v = (i < n) ? deg[i] : 0;
    s[t] = v;
    __syncthreads();
    for (int off = 1; off < 256; off <<= 1) {
        int add = (t >= off) ? s[t - off] : 0;
        __syncthreads();
        s[t] += add;
        __syncthreads();
    }
    if (i < n) row_ptr[i] = bsum[blockIdx.x] + s[t] - v;  // exclusive
    if (i == n - 1 && (n & 255) != 0) row_ptr[n] = bsum[blockIdx.x] + s[t];
    if (t == 255 && i == n - 1) row_ptr[n] = bsum[blockIdx.x] + s[255];
}

// pass 1: scatter {src,dst} into bucket regions; per-bucket cursors -> sequential writes
__global__ __launch_bounds__(256) void k_scatter1(const int* __restrict__ src, const int* __restrict__ dst,
                                                  int E, int* __restrict__ bcur, int2* __restrict__ tmp) {
    int e = blockIdx.x * 256 + threadIdx.x;
    if (e >= E) return;
    int s = src[e], d = dst[e];
    int pos = atomicAdd(&bcur[d >> 8], 1);
    tmp[pos] = make_int2(s, d);
}

// pass 2: one WG per bucket; LDS per-node cursors; dense contiguous output window in cw
__global__ __launch_bounds__(1024) void k_scatter2(const int2* __restrict__ tmp,
                                                   const int* __restrict__ row_ptr,
                                                   const float* __restrict__ inv,
                                                   int2* __restrict__ cw, int n) {
    __shared__ int lcur[256];
    int b = blockIdx.x;
    int node0 = b << 8;
    int nn = min(256, n - node0);
    int t = threadIdx.x;
    if (t < 256) lcur[t] = (t < nn) ? row_ptr[node0 + t] : 0;
    __syncthreads();
    int base = row_ptr[node0];
    int end = row_ptr[node0 + nn];
    for (int i = base + t; i < end; i += 1024) {
        int2 e = tmp[i];
        int pos = atomicAdd(&lcur[e.y - node0], 1);
        cw[pos] = make_int2(e.x, __float_as_int(inv[e.x]));
    }
}

// Y[n,64] = X[n,64] @ W[64,64]  (no bias). thread = (row, 16-col group)
__global__ __launch_bounds__(256) void k_gemm64(const float* __restrict__ X, const float* __restrict__ W,
                                                float* __restrict__ Y, int n) {
    __shared__ float Ws[FDIM * FDIM];
    int t = threadIdx.x;
    for (int i = t; i < FDIM * FDIM; i += 256) Ws[i] = W[i];
    __syncthreads();
    int idx = blockIdx.x * 256 + t;
    int row = idx >> 2;
    int cg = (idx & 3) * 16;
    if (row >= n) return;
    const float4* xr = (const float4*)(X + row * FDIM);
    float4 xv[16];
#pragma unroll
    for (int i = 0; i < 16; ++i) xv[i] = xr[i];
    float acc[16];
#pragma unroll
    for (int c = 0; c < 16; ++c) acc[c] = 0.f;
#pragma unroll
    for (int i = 0; i < 16; ++i) {
        float xs[4] = {xv[i].x, xv[i].y, xv[i].z, xv[i].w};
#pragma unroll
        for (int j = 0; j < 4; ++j) {
            float xk = xs[j];
            const float* wr = &Ws[(i * 4 + j) * FDIM + cg];
#pragma unroll
            for (int c = 0; c < 16; ++c) acc[c] += xk * wr[c];
        }
    }
    float4* yo = (float4*)(Y + row * FDIM + cg);
#pragma unroll
    for (int q = 0; q < 4; ++q)
        yo[q] = make_float4(acc[q * 4], acc[q * 4 + 1], acc[q * 4 + 2], acc[q * 4 + 3]);
}

// out[node][lane] = inv[d]*( sum_edges inv[s]*P[s][lane] + inv[d]*P[d][lane] ) + bias; opt relu
__global__ __launch_bounds__(256) void k_agg(const float* __restrict__ P, const float* __restrict__ inv,
                                             const int* __restrict__ row_ptr, const int2* __restrict__ cw,
                                             const float* __restrict__ bias,
                                             float* __restrict__ out, int n, int relu) {
    int wid = __builtin_amdgcn_readfirstlane(threadIdx.x >> 6);
    int lane = threadIdx.x & 63;
    int node = blockIdx.x * 4 + wid;
    if (node >= n) return;
    float iv = inv[node];
    float acc = P[node * FDIM + lane] * iv;   // self term (x iv again at end)
    int s = row_ptr[node], e = row_ptr[node + 1];
    // masked unroll x8: always 8 independent gathers in flight; tail gets weight 0
    for (int j = s; j < e; j += 8) {
        int2 a[8];
        float p[8];
        float wk[8];
#pragma unroll
        for (int k = 0; k < 8; ++k) {
            int jj = j + k;
            bool ok = jj < e;          // wave-uniform
            a[k] = cw[ok ? jj : s];
            wk[k] = ok ? __int_as_float(a[k].y) : 0.f;
        }
#pragma unroll
        for (int k = 0; k < 8; ++k) p[k] = P[(size_t)a[k].x * FDIM + lane];
#pragma unroll
        for (int k = 0; k < 8; ++k) acc = fmaf(wk[k], p[k], acc);
    }
    acc = fmaf(iv, acc, bias[lane]);
    if (relu) acc = fmaxf(acc, 0.f);
    out[node * FDIM + lane] = acc;
}

// out[n,16] = X[n,64] @ Wc[64,16] + bc. thread = (row, 4-col group)
__global__ __launch_bounds__(256) void k_cls(const float* __restrict__ X, const float* __restrict__ W,
                                             const float* __restrict__ b, float* __restrict__ Y, int n) {
    __shared__ float Ws[FDIM * NCLS];
    __shared__ float bs[NCLS];
    int t = threadIdx.x;
    for (int i = t; i < FDIM * NCLS; i += 256) Ws[i] = W[i];
    if (t < NCLS) bs[t] = b[t];
    __syncthreads();
    int idx = blockIdx.x * 256 + t;
    int row = idx >> 2;
    int cg = (idx & 3) * 4;
    if (row >= n) return;
    const float4* xr = (const float4*)(X + row * FDIM);
    float a0 = bs[cg], a1 = bs[cg + 1], a2 = bs[cg + 2], a3 = bs[cg + 3];
#pragma unroll
    for (int i = 0; i < 16; ++i) {
        float4 xq = xr[i];
        float xs[4] = {xq.x, xq.y, xq.z, xq.w};
#pragma unroll
        for (int j = 0; j < 4; ++j) {
            float xk = xs[j];
            const float* wr = &Ws[(i * 4 + j) * NCLS + cg];
            a0 += xk * wr[0];
            a1 += xk * wr[1];
            a2 += xk * wr[2];
            a3 += xk * wr[3];
        }
    }
    *(float4*)(Y + row * NCLS + cg) = make_float4(a0, a1, a2, a3);
}

static inline size_t align256(size_t x) { return (x + 255) & ~(size_t)255; }

extern "C" void kernel_launch(void* const* d_in, const int* in_sizes, int n_in,
                              void* d_out, int out_size, void* d_ws, size_t ws_size,
                              hipStream_t stream) {
    const float* x  = (const float*)d_in[0];
    const int*   ei = (const int*)d_in[1];
    const float* W1 = (const float*)d_in[2];
    const float* b1 = (const float*)d_in[3];
    const float* W2 = (const float*)d_in[4];
    const float* b2 = (const float*)d_in[5];
    const float* Wc = (const float*)d_in[6];
    const float* bc = (const float*)d_in[7];
    float* out = (float*)d_out;

    const int n = in_sizes[0] / FDIM;   // 50000
    const int E = in_sizes[1] / 2;      // 800000
    const int* src = ei;
    const int* dst = ei + E;

    // workspace carve-up
    char* w = (char*)d_ws;
    size_t off = 0;
    int* deg = (int*)(w + off);      off = align256(off + (size_t)n * 4);
    int* row_ptr = (int*)(w + off);  off = align256(off + (size_t)(n + 1) * 4);
    int* bsum = (int*)(w + off);     off = align256(off + 256 * 4);
    int* bcur = (int*)(w + off);     off = align256(off + 256 * 4);
    float* inv = (float*)(w + off);  off = align256(off + (size_t)n * 4);
    int2* cw = (int2*)(w + off);     off = align256(off + (size_t)E * 8);
    float* P = (float*)(w + off);    off = align256(off + (size_t)n * FDIM * 4);
    float* A = (float*)(w + off);    off = align256(off + (size_t)n * FDIM * 4);
    (void)ws_size;
    // staging buffer for pass1 aliases P: strictly dead before first gemm writes P
    int2* tmp = (int2*)P;

    const int nbE = (E + 255) / 256;
    const int nbN = (n + 255) / 256;   // 196 buckets of 256 nodes
    const int nbG = (n * 4 + 255) / 256;
    const int nbA = (n + 3) / 4;

    hipMemsetAsync(deg, 0, (size_t)n * 4, stream);

    // degree + inv + scans -> row_ptr, bucket bases
    k_deg<<<nbE, 256, 0, stream>>>(dst, E, deg);
    k_prep<<<nbN, 256, 0, stream>>>(deg, n, inv, bsum);
    k_scan_bsums<<<1, 256, 0, stream>>>(bsum, nbN, bcur);
    k_scan_chunks<<<nbN, 256, 0, stream>>>(deg, n, bsum, row_ptr);

    // 2-level counting sort into packed CSR
    k_scatter1<<<nbE, 256, 0, stream>>>(src, dst, E, bcur, tmp);
    k_scatter2<<<nbN, 1024, 0, stream>>>(tmp, row_ptr, inv, cw, n);

    // layer 1
    k_gemm64<<<nbG, 256, 0, stream>>>(x, W1, P, n);
    k_agg<<<nbA, 256, 0, stream>>>(P, inv, row_ptr, cw, b1, A, n, 1);
    // layer 2
    k_gemm64<<<nbG, 256, 0, stream>>>(A, W2, P, n);
    k_agg<<<nbA, 256, 0, stream>>>(P, inv, row_ptr, cw, b2, A, n, 1);
    // classifier
    k_cls<<<nbG, 256, 0, stream>>>(A, Wc, bc, out, n);
}

// Round 4
// 262.104 us; speedup vs baseline: 2.5927x; 2.5927x over previous
//
#include <hip/hip_runtime.h>
#include <hip/hip_bf16.h>

// GCN 2-layer + classifier, fp32.
// x:[n,64] edge_index:[2,E] int32, W1:[64,64] b1:[64] W2:[64,64] b2:[64] Wc:[64,16] bc:[16]
// out:[n,16] fp32.
// CSR-by-dst rebuilt per launch. R3 lesson: bucketed scatter (196 atomic cursors)
// serializes 800k RMWs -> 450us. Per-node cursors (50000) keep contention ~16/ctr: 48us.
// k_fill: one 8B {src, inv[src]} store per edge = one random line per edge.
// k_agg: 4 nodes/wave, 16 lanes x float4 per node row; unroll x4 -> 16 row-gathers
// in flight per wave, 1KB per gather instruction.

#define FDIM 64
#define NCLS 16

__global__ __launch_bounds__(256) void k_deg(const int* __restrict__ dst, int E, int* __restrict__ deg) {
    int e = blockIdx.x * 256 + threadIdx.x;
    if (e < E) atomicAdd(&deg[dst[e]], 1);
}

// inv = rsqrt(deg+1) fused with per-block degree sums (both read deg once)
__global__ __launch_bounds__(256) void k_prep(const int* __restrict__ deg, int n,
                                              float* __restrict__ inv, int* __restrict__ bsum) {
    __shared__ int s[256];
    int t = threadIdx.x;
    int i = blockIdx.x * 256 + t;
    int d = (i < n) ? deg[i] : 0;
    if (i < n) inv[i] = rsqrtf((float)(d + 1));
    s[t] = d;
    __syncthreads();
    for (int off = 128; off > 0; off >>= 1) {
        if (t < off) s[t] += s[t + off];
        __syncthreads();
    }
    if (t == 0) bsum[blockIdx.x] = s[0];
}

// single block, nb <= 256: exclusive scan of bsum, total -> *total
__global__ __launch_bounds__(256) void k_scan_bsums(int* __restrict__ bsum, int nb, int* __restrict__ total) {
    __shared__ int s[256];
    int t = threadIdx.x;
    int v = (t < nb) ? bsum[t] : 0;
    s[t] = v;
    __syncthreads();
    for (int off = 1; off < 256; off <<= 1) {
        int add = (t >= off) ? s[t - off] : 0;
        __syncthreads();
        s[t] += add;
        __syncthreads();
    }
    if (t < nb) bsum[t] = s[t] - v;   // exclusive
    if (t == 255) *total = s[255];
}

__global__ __launch_bounds__(256) void k_scan_chunks(const int* __restrict__ deg, int n,
                                                     const int* __restrict__ bsum, int* __restrict__ row_ptr) {
    __shared__ int s[256];
    int t = threadIdx.x;
    int i = blockIdx.x * 256 + t;
    int v = (i < n) ? deg[i] : 0;
    s[t] = v;
    __syncthreads();
    for (int off = 1; off < 256; off <<= 1) {
        int add = (t >= off) ? s[t - off] : 0;
        __syncthreads();
        s[t] += add;
        __syncthreads();
    }
    if (i < n) row_ptr[i] = bsum[blockIdx.x] + s[t] - v;  // exclusive
}

__global__ __launch_bounds__(256) void k_fill(const int* __restrict__ src, const int* __restrict__ dst, int E,
                                              const int* __restrict__ row_ptr, int* __restrict__ cnt,
                                              int2* __restrict__ cw, const float* __restrict__ inv) {
    int e = blockIdx.x * 256 + threadIdx.x;
    if (e >= E) return;
    int s = src[e], d = dst[e];
    int pos = row_ptr[d] + atomicAdd(&cnt[d], 1);
    cw[pos] = make_int2(s, __float_as_int(inv[s]));   // one 8B store, one random line
}

// Y[n,64] = X[n,64] @ W[64,64]  (no bias). thread = (row, 16-col group)
__global__ __launch_bounds__(256) void k_gemm64(const float* __restrict__ X, const float* __restrict__ W,
                                                float* __restrict__ Y, int n) {
    __shared__ float Ws[FDIM * FDIM];
    int t = threadIdx.x;
    for (int i = t; i < FDIM * FDIM; i += 256) Ws[i] = W[i];
    __syncthreads();
    int idx = blockIdx.x * 256 + t;
    int row = idx >> 2;
    int cg = (idx & 3) * 16;
    if (row >= n) return;
    const float4* xr = (const float4*)(X + row * FDIM);
    float4 xv[16];
#pragma unroll
    for (int i = 0; i < 16; ++i) xv[i] = xr[i];
    float acc[16];
#pragma unroll
    for (int c = 0; c < 16; ++c) acc[c] = 0.f;
#pragma unroll
    for (int i = 0; i < 16; ++i) {
        float xs[4] = {xv[i].x, xv[i].y, xv[i].z, xv[i].w};
#pragma unroll
        for (int j = 0; j < 4; ++j) {
            float xk = xs[j];
            const float* wr = &Ws[(i * 4 + j) * FDIM + cg];
#pragma unroll
            for (int c = 0; c < 16; ++c) acc[c] += xk * wr[c];
        }
    }
    float4* yo = (float4*)(Y + row * FDIM + cg);
#pragma unroll
    for (int q = 0; q < 4; ++q)
        yo[q] = make_float4(acc[q * 4], acc[q * 4 + 1], acc[q * 4 + 2], acc[q * 4 + 3]);
}

// 4 nodes per wave; 16 lanes x float4 cover one 64-float row.
// out[node] = inv[d]*( sum_edges inv[s]*P[s] + inv[d]*P[d] ) + bias; opt relu
__global__ __launch_bounds__(256) void k_agg(const float* __restrict__ P, const float* __restrict__ inv,
                                             const int* __restrict__ row_ptr, const int2* __restrict__ cw,
                                             const float* __restrict__ bias,
                                             float* __restrict__ out, int n, int relu) {
    int t = threadIdx.x;
    int lane = t & 63;
    int sub = lane >> 4;      // node slot within wave (0..3)
    int fl = lane & 15;       // float4 chunk within row
    int wid = t >> 6;         // wave within block
    int node = blockIdx.x * 16 + wid * 4 + sub;
    bool alive = node < n;
    int nodeC = alive ? node : (n - 1);
    float iv = inv[nodeC];
    const float4* P4 = (const float4*)P;
    float4 self = P4[(size_t)nodeC * 16 + fl];
    float4 acc = make_float4(self.x * iv, self.y * iv, self.z * iv, self.w * iv);
    int s = row_ptr[nodeC];
    int e = alive ? row_ptr[nodeC + 1] : s;
    int deg = e - s;
    // wave-max degree (deg uniform within each 16-lane subgroup)
    int dmax = deg;
    dmax = max(dmax, __shfl_xor(dmax, 16, 64));
    dmax = max(dmax, __shfl_xor(dmax, 32, 64));
    for (int j = 0; j < dmax; j += 4) {
        int2 a[4];
        float wk[4];
        float4 p[4];
#pragma unroll
        for (int k = 0; k < 4; ++k) {
            int jj = s + j + k;
            bool ok = jj < e;
            a[k] = cw[ok ? jj : s];
            wk[k] = ok ? __int_as_float(a[k].y) : 0.f;
        }
#pragma unroll
        for (int k = 0; k < 4; ++k) p[k] = P4[(size_t)a[k].x * 16 + fl];
#pragma unroll
        for (int k = 0; k < 4; ++k) {
            acc.x = fmaf(wk[k], p[k].x, acc.x);
            acc.y = fmaf(wk[k], p[k].y, acc.y);
            acc.z = fmaf(wk[k], p[k].z, acc.z);
            acc.w = fmaf(wk[k], p[k].w, acc.w);
        }
    }
    float4 bb = ((const float4*)bias)[fl];
    float4 r;
    r.x = fmaf(iv, acc.x, bb.x);
    r.y = fmaf(iv, acc.y, bb.y);
    r.z = fmaf(iv, acc.z, bb.z);
    r.w = fmaf(iv, acc.w, bb.w);
    if (relu) {
        r.x = fmaxf(r.x, 0.f); r.y = fmaxf(r.y, 0.f);
        r.z = fmaxf(r.z, 0.f); r.w = fmaxf(r.w, 0.f);
    }
    if (alive) ((float4*)out)[(size_t)node * 16 + fl] = r;
}

// out[n,16] = X[n,64] @ Wc[64,16] + bc. thread = (row, 4-col group)
__global__ __launch_bounds__(256) void k_cls(const float* __restrict__ X, const float* __restrict__ W,
                                             const float* __restrict__ b, float* __restrict__ Y, int n) {
    __shared__ float Ws[FDIM * NCLS];
    __shared__ float bs[NCLS];
    int t = threadIdx.x;
    for (int i = t; i < FDIM * NCLS; i += 256) Ws[i] = W[i];
    if (t < NCLS) bs[t] = b[t];
    __syncthreads();
    int idx = blockIdx.x * 256 + t;
    int row = idx >> 2;
    int cg = (idx & 3) * 4;
    if (row >= n) return;
    const float4* xr = (const float4*)(X + row * FDIM);
    float a0 = bs[cg], a1 = bs[cg + 1], a2 = bs[cg + 2], a3 = bs[cg + 3];
#pragma unroll
    for (int i = 0; i < 16; ++i) {
        float4 xq = xr[i];
        float xs[4] = {xq.x, xq.y, xq.z, xq.w};
#pragma unroll
        for (int j = 0; j < 4; ++j) {
            float xk = xs[j];
            const float* wr = &Ws[(i * 4 + j) * NCLS + cg];
            a0 += xk * wr[0];
            a1 += xk * wr[1];
            a2 += xk * wr[2];
            a3 += xk * wr[3];
        }
    }
    *(float4*)(Y + row * NCLS + cg) = make_float4(a0, a1, a2, a3);
}

static inline size_t align256(size_t x) { return (x + 255) & ~(size_t)255; }

extern "C" void kernel_launch(void* const* d_in, const int* in_sizes, int n_in,
                              void* d_out, int out_size, void* d_ws, size_t ws_size,
                              hipStream_t stream) {
    const float* x  = (const float*)d_in[0];
    const int*   ei = (const int*)d_in[1];
    const float* W1 = (const float*)d_in[2];
    const float* b1 = (const float*)d_in[3];
    const float* W2 = (const float*)d_in[4];
    const float* b2 = (const float*)d_in[5];
    const float* Wc = (const float*)d_in[6];
    const float* bc = (const float*)d_in[7];
    float* out = (float*)d_out;

    const int n = in_sizes[0] / FDIM;   // 50000
    const int E = in_sizes[1] / 2;      // 800000
    const int* src = ei;
    const int* dst = ei + E;

    // workspace carve-up
    char* w = (char*)d_ws;
    size_t off = 0;
    int* deg = (int*)(w + off);      off = align256(off + (size_t)n * 4);
    int* cnt = (int*)(w + off);      off = align256(off + (size_t)n * 4);
    int* row_ptr = (int*)(w + off);  off = align256(off + (size_t)(n + 1) * 4);
    int* bsum = (int*)(w + off);     off = align256(off + 256 * 4);
    float* inv = (float*)(w + off);  off = align256(off + (size_t)n * 4);
    int2* cw = (int2*)(w + off);     off = align256(off + (size_t)E * 8);
    float* P = (float*)(w + off);    off = align256(off + (size_t)n * FDIM * 4);
    float* A = (float*)(w + off);    off = align256(off + (size_t)n * FDIM * 4);
    (void)ws_size;

    const int nbE = (E + 255) / 256;
    const int nbN = (n + 255) / 256;
    const int nbG = (n * 4 + 255) / 256;
    const int nbA = (n + 15) / 16;     // 16 nodes per block (4 waves x 4 nodes)

    hipMemsetAsync(deg, 0, (size_t)n * 4, stream);
    hipMemsetAsync(cnt, 0, (size_t)n * 4, stream);

    // degree + inv + scan -> row_ptr  (nbN = 196 <= 256 fits one-block scan)
    k_deg<<<nbE, 256, 0, stream>>>(dst, E, deg);
    k_prep<<<nbN, 256, 0, stream>>>(deg, n, inv, bsum);
    k_scan_bsums<<<1, 256, 0, stream>>>(bsum, nbN, row_ptr + n);
    k_scan_chunks<<<nbN, 256, 0, stream>>>(deg, n, bsum, row_ptr);

    // fill packed CSR
    k_fill<<<nbE, 256, 0, stream>>>(src, dst, E, row_ptr, cnt, cw, inv);

    // layer 1
    k_gemm64<<<nbG, 256, 0, stream>>>(x, W1, P, n);
    k_agg<<<nbA, 256, 0, stream>>>(P, inv, row_ptr, cw, b1, A, n, 1);
    // layer 2
    k_gemm64<<<nbG, 256, 0, stream>>>(A, W2, P, n);
    k_agg<<<nbA, 256, 0, stream>>>(P, inv, row_ptr, cw, b2, A, n, 1);
    // classifier
    k_cls<<<nbG, 256, 0, stream>>>(A, Wc, bc, out, n);
}